// Round 2
// baseline (898.439 us; speedup 1.0000x reference)
//
#include <hip/hip_runtime.h>
#include <hip/hip_bf16.h>

#define N_NODES 50000
#define N_EDGES 800000
#define D 128
#define H 8
#define DH 16
#define NB 8   // nodes per projection block

// ---------------------------------------------------------------------------
// Kernel 1: Q/K/V projections (f32) + zero-init wV, z.
// Block = 128 threads, handles NB nodes. x rows staged in LDS; thread d
// computes Q/K/V[n][d] for all NB nodes, so each W element is loaded once
// per NB nodes (3*64KB W set stays L2-resident; ~1.2 GB total L2 traffic).
// ---------------------------------------------------------------------------
__global__ __launch_bounds__(128) void proj_kernel(
    const float* __restrict__ x,
    const float* __restrict__ Wq, const float* __restrict__ bq,
    const float* __restrict__ Wk, const float* __restrict__ bk,
    const float* __restrict__ Wv, const float* __restrict__ bv,
    float* __restrict__ Q, float* __restrict__ K, float* __restrict__ V,
    float* __restrict__ wV, float* __restrict__ z)
{
    const int n0 = blockIdx.x * NB;
    const int d  = threadIdx.x;

    __shared__ float xs[NB][D];
    #pragma unroll
    for (int i = 0; i < NB; ++i) {
        int n = n0 + i;
        xs[i][d] = (n < N_NODES) ? x[n * D + d] : 0.0f;
    }
    __syncthreads();

    float aq[NB], ak[NB], av[NB];
    const float vbq = bq[d], vbk = bk[d], vbv = bv[d];
    #pragma unroll
    for (int i = 0; i < NB; ++i) { aq[i] = vbq; ak[i] = vbk; av[i] = vbv; }

    for (int k = 0; k < D; ++k) {
        const float wq = Wq[k * D + d];
        const float wk = Wk[k * D + d];
        const float wv = Wv[k * D + d];
        #pragma unroll
        for (int i = 0; i < NB; ++i) {
            const float xv = xs[i][k];
            aq[i] += xv * wq;
            ak[i] += xv * wk;
            av[i] += xv * wv;
        }
    }

    #pragma unroll
    for (int i = 0; i < NB; ++i) {
        const int n = n0 + i;
        if (n < N_NODES) {
            Q[n * D + d] = aq[i];
            K[n * D + d] = ak[i];
            V[n * D + d] = av[i];
            wV[n * D + d] = 0.0f;              // zero accumulators (ws poisoned 0xAA)
            if (d < H) z[n * H + d] = 0.0f;
        }
    }
}

// ---------------------------------------------------------------------------
// Kernel 2: per-edge scores + atomic scatter into wV / z.
// One wave (64 lanes) per edge, grid-stride. Lane l owns dims {2l, 2l+1},
// both in head h = l>>3; the 8-lane group {8h..8h+7} covers head h.
// ---------------------------------------------------------------------------
__global__ __launch_bounds__(256) void edge_kernel(
    const int* __restrict__ src, const int* __restrict__ dst,
    const float* __restrict__ Q, const float* __restrict__ K,
    const float* __restrict__ V,
    float* __restrict__ wV, float* __restrict__ z)
{
    const int lane   = threadIdx.x & 63;
    const int wave   = (blockIdx.x * blockDim.x + threadIdx.x) >> 6;
    const int nwaves = (gridDim.x * blockDim.x) >> 6;

    for (int e = wave; e < N_EDGES; e += nwaves) {
        const int s = src[e];
        const int t = dst[e];

        const float2 kv = *(const float2*)(K + s * D + lane * 2);
        const float2 qv = *(const float2*)(Q + t * D + lane * 2);

        float partial = kv.x * qv.x + kv.y * qv.y;
        partial += __shfl_xor(partial, 1);
        partial += __shfl_xor(partial, 2);
        partial += __shfl_xor(partial, 4);

        const float arg = fminf(fmaxf(partial * 0.25f, -5.0f), 5.0f);
        const float w = __expf(arg);

        const float2 vv = *(const float2*)(V + s * D + lane * 2);
        atomicAdd(wV + t * D + lane * 2 + 0, w * vv.x);
        atomicAdd(wV + t * D + lane * 2 + 1, w * vv.y);
        if ((lane & 7) == 0) atomicAdd(z + t * H + (lane >> 3), w);
    }
}

// ---------------------------------------------------------------------------
// Kernel 3: out = x + wV / z   (normalize + residual), f32 out
// ---------------------------------------------------------------------------
__global__ __launch_bounds__(256) void final_kernel(
    const float* __restrict__ x,
    const float* __restrict__ wV, const float* __restrict__ z,
    float* __restrict__ out)
{
    const int i = blockIdx.x * blockDim.x + threadIdx.x;
    if (i >= N_NODES * D) return;
    const int n = i >> 7;        // / D
    const int d = i & (D - 1);
    const float denom = z[n * H + (d >> 4)];
    out[i] = x[i] + wV[i] / denom;
}

// ---------------------------------------------------------------------------
extern "C" void kernel_launch(void* const* d_in, const int* in_sizes, int n_in,
                              void* d_out, int out_size, void* d_ws, size_t ws_size,
                              hipStream_t stream) {
    const float* x   = (const float*)d_in[0];
    const int*   src = (const int*)d_in[1];
    const int*   dst = (const int*)d_in[2];
    const float* Wq  = (const float*)d_in[3];
    const float* bq  = (const float*)d_in[4];
    const float* Wk  = (const float*)d_in[5];
    const float* bk  = (const float*)d_in[6];
    const float* Wv  = (const float*)d_in[7];
    const float* bv  = (const float*)d_in[8];

    float* ws = (float*)d_ws;
    float* Q  = ws;
    float* K  = Q  + (size_t)N_NODES * D;
    float* V  = K  + (size_t)N_NODES * D;
    float* wV = V  + (size_t)N_NODES * D;
    float* z  = wV + (size_t)N_NODES * D;
    // total: 4*50000*128 + 50000*8 floats = 104 MB of d_ws

    float* out = (float*)d_out;

    proj_kernel<<<(N_NODES + NB - 1) / NB, 128, 0, stream>>>(
        x, Wq, bq, Wk, bk, Wv, bv, Q, K, V, wV, z);

    // 2048 blocks x 256 threads = 8192 waves, ~98 edges/wave
    edge_kernel<<<2048, 256, 0, stream>>>(src, dst, Q, K, V, wV, z);

    final_kernel<<<(N_NODES * D + 255) / 256, 256, 0, stream>>>(x, wV, z, out);
}

// Round 3
// 420.591 us; speedup vs baseline: 2.1361x; 2.1361x over previous
//
#include <hip/hip_runtime.h>
#include <hip/hip_bf16.h>

#define N_NODES 50000
#define N_EDGES 800000
#define D 128
#define H 8
#define DH 16
#define NB 8            // nodes per projection block
#define SCAN_CHUNK 256
#define NCHUNK ((N_NODES + SCAN_CHUNK - 1) / SCAN_CHUNK)   // 196

// ---------------------------------------------------------------------------
// Kernel 1: Q/K/V projections (f32). Block = 128 threads, NB nodes staged in
// LDS; thread d computes Q/K/V[n][d] for all NB nodes.
// ---------------------------------------------------------------------------
__global__ __launch_bounds__(128) void proj_kernel(
    const float* __restrict__ x,
    const float* __restrict__ Wq, const float* __restrict__ bq,
    const float* __restrict__ Wk, const float* __restrict__ bk,
    const float* __restrict__ Wv, const float* __restrict__ bv,
    float* __restrict__ Q, float* __restrict__ K, float* __restrict__ V)
{
    const int n0 = blockIdx.x * NB;
    const int d  = threadIdx.x;

    __shared__ float xs[NB][D];
    #pragma unroll
    for (int i = 0; i < NB; ++i) {
        int n = n0 + i;
        xs[i][d] = (n < N_NODES) ? x[n * D + d] : 0.0f;
    }
    __syncthreads();

    float aq[NB], ak[NB], av[NB];
    const float vbq = bq[d], vbk = bk[d], vbv = bv[d];
    #pragma unroll
    for (int i = 0; i < NB; ++i) { aq[i] = vbq; ak[i] = vbk; av[i] = vbv; }

    for (int k = 0; k < D; ++k) {
        const float wq = Wq[k * D + d];
        const float wk = Wk[k * D + d];
        const float wv = Wv[k * D + d];
        #pragma unroll
        for (int i = 0; i < NB; ++i) {
            const float xv = xs[i][k];
            aq[i] += xv * wq;
            ak[i] += xv * wk;
            av[i] += xv * wv;
        }
    }

    #pragma unroll
    for (int i = 0; i < NB; ++i) {
        const int n = n0 + i;
        if (n < N_NODES) {
            Q[n * D + d] = aq[i];
            K[n * D + d] = ak[i];
            V[n * D + d] = av[i];
        }
    }
}

// ---------------------------------------------------------------------------
// CSR build: zero counts -> histogram -> 3-step exclusive scan -> scatter
// ---------------------------------------------------------------------------
__global__ __launch_bounds__(256) void zero_counts_kernel(int* __restrict__ counts)
{
    const int i = blockIdx.x * blockDim.x + threadIdx.x;
    if (i < N_NODES) counts[i] = 0;
}

__global__ __launch_bounds__(256) void hist_kernel(
    const int* __restrict__ dst, int* __restrict__ counts)
{
    const int i = blockIdx.x * blockDim.x + threadIdx.x;
    const int stride = gridDim.x * blockDim.x;
    for (int e = i; e < N_EDGES; e += stride)
        atomicAdd(&counts[dst[e]], 1);
}

// per-chunk exclusive scan; chunk totals to blksums
__global__ __launch_bounds__(SCAN_CHUNK) void scan_a_kernel(
    const int* __restrict__ counts, int* __restrict__ row_ptr,
    int* __restrict__ blksums)
{
    __shared__ int sd[SCAN_CHUNK];
    const int tid = threadIdx.x;
    const int i   = blockIdx.x * SCAN_CHUNK + tid;
    const int v   = (i < N_NODES) ? counts[i] : 0;
    sd[tid] = v;
    __syncthreads();
    #pragma unroll
    for (int off = 1; off < SCAN_CHUNK; off <<= 1) {
        int t = (tid >= off) ? sd[tid - off] : 0;
        __syncthreads();
        sd[tid] += t;
        __syncthreads();
    }
    if (i < N_NODES) row_ptr[i] = sd[tid] - v;     // exclusive
    if (tid == 0) blksums[blockIdx.x] = sd[SCAN_CHUNK - 1];
}

// scan the 196 chunk totals (exclusive), in place
__global__ __launch_bounds__(SCAN_CHUNK) void scan_b_kernel(int* __restrict__ blksums)
{
    __shared__ int sd[SCAN_CHUNK];
    const int tid = threadIdx.x;
    const int v = (tid < NCHUNK) ? blksums[tid] : 0;
    sd[tid] = v;
    __syncthreads();
    #pragma unroll
    for (int off = 1; off < SCAN_CHUNK; off <<= 1) {
        int t = (tid >= off) ? sd[tid - off] : 0;
        __syncthreads();
        sd[tid] += t;
        __syncthreads();
    }
    if (tid < NCHUNK) blksums[tid] = sd[tid] - v;  // exclusive
}

// add chunk offsets; init cursor copy; set sentinel
__global__ __launch_bounds__(256) void scan_c_kernel(
    int* __restrict__ row_ptr, const int* __restrict__ blksums,
    int* __restrict__ cursor)
{
    const int i = blockIdx.x * blockDim.x + threadIdx.x;
    if (i < N_NODES) {
        const int rp = row_ptr[i] + blksums[i >> 8];
        row_ptr[i] = rp;
        cursor[i] = rp;
    }
    if (i == 0) row_ptr[N_NODES] = N_EDGES;
}

__global__ __launch_bounds__(256) void scatter_kernel(
    const int* __restrict__ dst, int* __restrict__ cursor,
    int* __restrict__ edge_ids)
{
    const int i = blockIdx.x * blockDim.x + threadIdx.x;
    const int stride = gridDim.x * blockDim.x;
    for (int e = i; e < N_EDGES; e += stride) {
        const int pos = atomicAdd(&cursor[dst[e]], 1);
        edge_ids[pos] = e;
    }
}

// ---------------------------------------------------------------------------
// Aggregate: one wave per dst node. Lane l owns dims {2l,2l+1} (head l>>3).
// Walks the node's CSR edge list, accumulates w*V[src] and z in registers,
// writes out = x + acc/z directly (final_kernel fused).
// ---------------------------------------------------------------------------
__global__ __launch_bounds__(256) void aggregate_kernel(
    const int* __restrict__ src,
    const int* __restrict__ row_ptr, const int* __restrict__ edge_ids,
    const float* __restrict__ Q, const float* __restrict__ K,
    const float* __restrict__ V, const float* __restrict__ x,
    float* __restrict__ out)
{
    const int lane = threadIdx.x & 63;
    const int t    = (blockIdx.x * blockDim.x + threadIdx.x) >> 6;  // node id
    if (t >= N_NODES) return;

    const float2 q = *(const float2*)(Q + t * D + lane * 2);

    const int rp0 = row_ptr[t];
    const int rp1 = row_ptr[t + 1];

    float accx = 0.0f, accy = 0.0f, zh = 0.0f;

    for (int i = rp0; i < rp1; ++i) {
        const int e = edge_ids[i];
        const int s = src[e];

        const float2 kv = *(const float2*)(K + s * D + lane * 2);
        const float2 vv = *(const float2*)(V + s * D + lane * 2);

        float partial = kv.x * q.x + kv.y * q.y;
        partial += __shfl_xor(partial, 1);
        partial += __shfl_xor(partial, 2);
        partial += __shfl_xor(partial, 4);

        const float arg = fminf(fmaxf(partial * 0.25f, -5.0f), 5.0f);
        const float w = __expf(arg);

        accx += w * vv.x;
        accy += w * vv.y;
        zh   += w;            // same value across the 8 lanes of this head
    }

    const float inv = 1.0f / zh;
    const int base = t * D + lane * 2;
    out[base + 0] = x[base + 0] + accx * inv;
    out[base + 1] = x[base + 1] + accy * inv;
}

// ---------------------------------------------------------------------------
extern "C" void kernel_launch(void* const* d_in, const int* in_sizes, int n_in,
                              void* d_out, int out_size, void* d_ws, size_t ws_size,
                              hipStream_t stream) {
    const float* x   = (const float*)d_in[0];
    const int*   src = (const int*)d_in[1];
    const int*   dst = (const int*)d_in[2];
    const float* Wq  = (const float*)d_in[3];
    const float* bq  = (const float*)d_in[4];
    const float* Wk  = (const float*)d_in[5];
    const float* bk  = (const float*)d_in[6];
    const float* Wv  = (const float*)d_in[7];
    const float* bv  = (const float*)d_in[8];

    float* ws = (float*)d_ws;
    float* Q = ws;
    float* K = Q + (size_t)N_NODES * D;
    float* V = K + (size_t)N_NODES * D;
    int* ip       = (int*)(V + (size_t)N_NODES * D);
    int* counts   = ip;                    // [50048]
    int* row_ptr  = counts + 50048;        // [50048] (+ sentinel)
    int* cursor   = row_ptr + 50048;       // [50048]
    int* blksums  = cursor + 50048;        // [256]
    int* edge_ids = blksums + 256;         // [800000]
    // total ws: 76.8 MB floats + ~3.8 MB ints

    float* out = (float*)d_out;

    proj_kernel<<<(N_NODES + NB - 1) / NB, 128, 0, stream>>>(
        x, Wq, bq, Wk, bk, Wv, bv, Q, K, V);

    zero_counts_kernel<<<(N_NODES + 255) / 256, 256, 0, stream>>>(counts);
    hist_kernel<<<1024, 256, 0, stream>>>(dst, counts);
    scan_a_kernel<<<NCHUNK, SCAN_CHUNK, 0, stream>>>(counts, row_ptr, blksums);
    scan_b_kernel<<<1, SCAN_CHUNK, 0, stream>>>(blksums);
    scan_c_kernel<<<(N_NODES + 255) / 256, 256, 0, stream>>>(row_ptr, blksums, cursor);
    scatter_kernel<<<1024, 256, 0, stream>>>(dst, cursor, edge_ids);

    // one wave per node: 50000 waves, 4 waves/block
    aggregate_kernel<<<(N_NODES * 64 + 255) / 256, 256, 0, stream>>>(
        src, row_ptr, edge_ids, Q, K, V, x, out);
}

// Round 4
// 351.597 us; speedup vs baseline: 2.5553x; 1.1962x over previous
//
#include <hip/hip_runtime.h>
#include <hip/hip_bf16.h>

#define N_NODES 50000
#define N_EDGES 800000
#define D 128
#define H 8
#define DH 16
#define SCAN_CHUNK 256
#define NCHUNK ((N_NODES + SCAN_CHUNK - 1) / SCAN_CHUNK)   // 196

typedef __attribute__((ext_vector_type(8))) short short8;
typedef __attribute__((ext_vector_type(4))) float floatx4;

__device__ __forceinline__ float bfbits2f(unsigned short u) {
    union { unsigned int i; float f; } c; c.i = ((unsigned int)u) << 16; return c.f;
}
__device__ __forceinline__ short f2bfbits(float f) {
    __hip_bfloat16 h = __float2bfloat16(f);
    return *reinterpret_cast<short*>(&h);
}

// ---------------------------------------------------------------------------
// Prep: Wt[p][col][k] = bf16(W_p[k][col])  (transposed, bf16) — 3*128*128
// ---------------------------------------------------------------------------
__global__ __launch_bounds__(256) void prep_w_kernel(
    const float* __restrict__ Wq, const float* __restrict__ Wk,
    const float* __restrict__ Wv, __hip_bfloat16* __restrict__ Wt)
{
    const int i = blockIdx.x * 256 + threadIdx.x;
    if (i >= 3 * D * D) return;
    const int p = i >> 14;
    const int r = i & (D * D - 1);
    const int col = r >> 7;
    const int k = r & (D - 1);
    const float* W = (p == 0) ? Wq : (p == 1) ? Wk : Wv;
    Wt[i] = __float2bfloat16(W[k * D + col]);
}

// ---------------------------------------------------------------------------
// Projections via bf16 MFMA, f32 accum. Grid (ceil(N/32), 3); 256 thr = 4 waves.
// Block = 32 nodes x 128 cols of projection p. Wave w owns cols [w*32, w*32+32).
// A frags direct from f32 x (cvt in reg); B frags direct from bf16 Wt (L2-hot).
// D mapping (verified): col = lane&15, row = (lane>>4)*4 + r.
// A: row = lane&15, k = (lane>>4)*8 + j.  B: col = lane&15, k = (lane>>4)*8 + j.
// ---------------------------------------------------------------------------
__global__ __launch_bounds__(256) void proj_mfma_kernel(
    const float* __restrict__ x,
    const __hip_bfloat16* __restrict__ Wt,
    const float* __restrict__ bq, const float* __restrict__ bk,
    const float* __restrict__ bv,
    __hip_bfloat16* __restrict__ Qb,     // [N][128]
    __hip_bfloat16* __restrict__ KVi)    // [N][256]: [2d]=K, [2d+1]=V
{
    const int p    = blockIdx.y;
    const int m0   = blockIdx.x * 32;
    const int lane = threadIdx.x & 63;
    const int wv   = threadIdx.x >> 6;
    const int cb   = wv * 32;

    const short* Wp = (const short*)(Wt + p * D * D);

    floatx4 acc[2][2];
    #pragma unroll
    for (int a = 0; a < 2; ++a)
        #pragma unroll
        for (int b = 0; b < 2; ++b)
            acc[a][b] = (floatx4){0.f, 0.f, 0.f, 0.f};

    const int lr = lane & 15;
    const int lk = (lane >> 4) * 8;

    #pragma unroll
    for (int ks = 0; ks < 4; ++ks) {
        const int k0 = ks * 32 + lk;
        short8 afr[2];
        #pragma unroll
        for (int rt = 0; rt < 2; ++rt) {
            int node = m0 + rt * 16 + lr;
            if (node > N_NODES - 1) node = N_NODES - 1;   // clamp OOB loads
            const float4 f0 = *(const float4*)(x + node * D + k0);
            const float4 f1 = *(const float4*)(x + node * D + k0 + 4);
            afr[rt][0] = f2bfbits(f0.x); afr[rt][1] = f2bfbits(f0.y);
            afr[rt][2] = f2bfbits(f0.z); afr[rt][3] = f2bfbits(f0.w);
            afr[rt][4] = f2bfbits(f1.x); afr[rt][5] = f2bfbits(f1.y);
            afr[rt][6] = f2bfbits(f1.z); afr[rt][7] = f2bfbits(f1.w);
        }
        #pragma unroll
        for (int ct = 0; ct < 2; ++ct) {
            const int col = cb + ct * 16 + lr;
            const short8 bfr = *(const short8*)(Wp + col * D + k0);
            acc[0][ct] = __builtin_amdgcn_mfma_f32_16x16x32_bf16(afr[0], bfr, acc[0][ct], 0, 0, 0);
            acc[1][ct] = __builtin_amdgcn_mfma_f32_16x16x32_bf16(afr[1], bfr, acc[1][ct], 0, 0, 0);
        }
    }

    const float* bias = (p == 0) ? bq : (p == 1) ? bk : bv;
    #pragma unroll
    for (int rt = 0; rt < 2; ++rt) {
        #pragma unroll
        for (int ct = 0; ct < 2; ++ct) {
            const int col = cb + ct * 16 + lr;
            const float bsv = bias[col];
            #pragma unroll
            for (int r = 0; r < 4; ++r) {
                const int node = m0 + rt * 16 + (lane >> 4) * 4 + r;
                if (node < N_NODES) {
                    const float val = acc[rt][ct][r] + bsv;
                    if (p == 0)      Qb [node * D + col]              = __float2bfloat16(val);
                    else if (p == 1) KVi[node * 2 * D + 2 * col]      = __float2bfloat16(val);
                    else             KVi[node * 2 * D + 2 * col + 1]  = __float2bfloat16(val);
                }
            }
        }
    }
}

// ---------------------------------------------------------------------------
// CSR build: zero -> histogram -> 3-step exclusive scan -> scatter (srcs)
// ---------------------------------------------------------------------------
__global__ __launch_bounds__(256) void zero_counts_kernel(int* __restrict__ counts)
{
    const int i = blockIdx.x * blockDim.x + threadIdx.x;
    if (i < N_NODES) counts[i] = 0;
}

__global__ __launch_bounds__(256) void hist_kernel(
    const int* __restrict__ dst, int* __restrict__ counts)
{
    const int i = blockIdx.x * blockDim.x + threadIdx.x;
    const int stride = gridDim.x * blockDim.x;
    for (int e = i; e < N_EDGES; e += stride)
        atomicAdd(&counts[dst[e]], 1);
}

__global__ __launch_bounds__(SCAN_CHUNK) void scan_a_kernel(
    const int* __restrict__ counts, int* __restrict__ row_ptr,
    int* __restrict__ blksums)
{
    __shared__ int sd[SCAN_CHUNK];
    const int tid = threadIdx.x;
    const int i   = blockIdx.x * SCAN_CHUNK + tid;
    const int v   = (i < N_NODES) ? counts[i] : 0;
    sd[tid] = v;
    __syncthreads();
    #pragma unroll
    for (int off = 1; off < SCAN_CHUNK; off <<= 1) {
        int t = (tid >= off) ? sd[tid - off] : 0;
        __syncthreads();
        sd[tid] += t;
        __syncthreads();
    }
    if (i < N_NODES) row_ptr[i] = sd[tid] - v;
    if (tid == 0) blksums[blockIdx.x] = sd[SCAN_CHUNK - 1];
}

__global__ __launch_bounds__(SCAN_CHUNK) void scan_b_kernel(int* __restrict__ blksums)
{
    __shared__ int sd[SCAN_CHUNK];
    const int tid = threadIdx.x;
    const int v = (tid < NCHUNK) ? blksums[tid] : 0;
    sd[tid] = v;
    __syncthreads();
    #pragma unroll
    for (int off = 1; off < SCAN_CHUNK; off <<= 1) {
        int t = (tid >= off) ? sd[tid - off] : 0;
        __syncthreads();
        sd[tid] += t;
        __syncthreads();
    }
    if (tid < NCHUNK) blksums[tid] = sd[tid] - v;
}

__global__ __launch_bounds__(256) void scan_c_kernel(
    int* __restrict__ row_ptr, const int* __restrict__ blksums,
    int* __restrict__ cursor)
{
    const int i = blockIdx.x * blockDim.x + threadIdx.x;
    if (i < N_NODES) {
        const int rp = row_ptr[i] + blksums[i >> 8];
        row_ptr[i] = rp;
        cursor[i] = rp;
    }
    if (i == 0) row_ptr[N_NODES] = N_EDGES;
}

__global__ __launch_bounds__(256) void scatter_kernel(
    const int* __restrict__ dst, const int* __restrict__ src,
    int* __restrict__ cursor, int* __restrict__ srcs)
{
    const int i = blockIdx.x * blockDim.x + threadIdx.x;
    const int stride = gridDim.x * blockDim.x;
    for (int e = i; e < N_EDGES; e += stride) {
        const int pos = atomicAdd(&cursor[dst[e]], 1);
        srcs[pos] = src[e];
    }
}

// ---------------------------------------------------------------------------
// Aggregate: one wave per dst node. Lane l owns dims {2l,2l+1} (head l>>3).
// One contiguous 512B KVi row per edge (one b64 load/lane). Fused epilogue.
// ---------------------------------------------------------------------------
__global__ __launch_bounds__(256) void aggregate_kernel(
    const int* __restrict__ row_ptr, const int* __restrict__ srcs,
    const __hip_bfloat16* __restrict__ Qb, const __hip_bfloat16* __restrict__ KVi,
    const float* __restrict__ x, float* __restrict__ out)
{
    const int lane = threadIdx.x & 63;
    const int t    = (blockIdx.x * blockDim.x + threadIdx.x) >> 6;
    if (t >= N_NODES) return;

    const unsigned int qbits = *(const unsigned int*)((const short*)Qb + t * D + 2 * lane);
    const float q0 = bfbits2f((unsigned short)(qbits & 0xffff));
    const float q1 = bfbits2f((unsigned short)(qbits >> 16));

    const int rp0 = row_ptr[t];
    const int rp1 = row_ptr[t + 1];

    float accx = 0.f, accy = 0.f, zh = 0.f;

    for (int i = rp0; i < rp1; ++i) {
        const int s = srcs[i];
        const ushort4 kv = *(const ushort4*)((const short*)KVi + s * 2 * D + 4 * lane);
        const float kk0 = bfbits2f(kv.x), vv0 = bfbits2f(kv.y);
        const float kk1 = bfbits2f(kv.z), vv1 = bfbits2f(kv.w);

        float partial = kk0 * q0 + kk1 * q1;
        partial += __shfl_xor(partial, 1);
        partial += __shfl_xor(partial, 2);
        partial += __shfl_xor(partial, 4);

        const float arg = fminf(fmaxf(partial * 0.25f, -5.0f), 5.0f);
        const float w = __expf(arg);

        accx += w * vv0;
        accy += w * vv1;
        zh   += w;
    }

    const float inv = 1.0f / zh;
    const int base = t * D + 2 * lane;
    out[base + 0] = x[base + 0] + accx * inv;
    out[base + 1] = x[base + 1] + accy * inv;
}

// ---------------------------------------------------------------------------
extern "C" void kernel_launch(void* const* d_in, const int* in_sizes, int n_in,
                              void* d_out, int out_size, void* d_ws, size_t ws_size,
                              hipStream_t stream) {
    const float* x   = (const float*)d_in[0];
    const int*   src = (const int*)d_in[1];
    const int*   dst = (const int*)d_in[2];
    const float* Wq  = (const float*)d_in[3];
    const float* bq  = (const float*)d_in[4];
    const float* Wk  = (const float*)d_in[5];
    const float* bk  = (const float*)d_in[6];
    const float* Wv  = (const float*)d_in[7];
    const float* bv  = (const float*)d_in[8];

    __hip_bfloat16* Qb  = (__hip_bfloat16*)d_ws;                 // [N*D]
    __hip_bfloat16* KVi = Qb + (size_t)N_NODES * D;              // [N*2D]
    __hip_bfloat16* Wt  = KVi + (size_t)N_NODES * 2 * D;         // [3*D*D]
    int* counts   = (int*)(Wt + 3 * D * D);                      // [50048]
    int* row_ptr  = counts + 50048;                              // [50048]
    int* cursor   = row_ptr + 50048;                             // [50048]
    int* blksums  = cursor + 50048;                              // [256]
    int* srcs     = blksums + 256;                               // [800000]
    // total ws ~ 42.3 MB

    float* out = (float*)d_out;

    prep_w_kernel<<<(3 * D * D + 255) / 256, 256, 0, stream>>>(Wq, Wk, Wv, Wt);

    proj_mfma_kernel<<<dim3((N_NODES + 31) / 32, 3), 256, 0, stream>>>(
        x, Wt, bq, bk, bv, Qb, KVi);

    zero_counts_kernel<<<(N_NODES + 255) / 256, 256, 0, stream>>>(counts);
    hist_kernel<<<1024, 256, 0, stream>>>(dst, counts);
    scan_a_kernel<<<NCHUNK, SCAN_CHUNK, 0, stream>>>(counts, row_ptr, blksums);
    scan_b_kernel<<<1, SCAN_CHUNK, 0, stream>>>(blksums);
    scan_c_kernel<<<(N_NODES + 255) / 256, 256, 0, stream>>>(row_ptr, blksums, cursor);
    scatter_kernel<<<1024, 256, 0, stream>>>(dst, src, cursor, srcs);

    aggregate_kernel<<<(N_NODES * 64 + 255) / 256, 256, 0, stream>>>(
        row_ptr, srcs, Qb, KVi, x, out);
}

// Round 5
// 316.103 us; speedup vs baseline: 2.8422x; 1.1123x over previous
//
#include <hip/hip_runtime.h>
#include <hip/hip_bf16.h>

#define N_NODES 50000
#define N_EDGES 800000
#define D 128
#define H 8
#define DH 16
#define SCAN_CHUNK 256
#define NCHUNK ((N_NODES + SCAN_CHUNK - 1) / SCAN_CHUNK)   // 196

typedef __attribute__((ext_vector_type(8))) short short8;
typedef __attribute__((ext_vector_type(4))) float floatx4;

__device__ __forceinline__ float bfbits2f(unsigned short u) {
    union { unsigned int i; float f; } c; c.i = ((unsigned int)u) << 16; return c.f;
}
__device__ __forceinline__ short f2bfbits(float f) {
    __hip_bfloat16 h = __float2bfloat16(f);
    return *reinterpret_cast<short*>(&h);
}

// ---------------------------------------------------------------------------
// Prep: Wt[p][col][k] = bf16(W_p[k][col]) + zero the counts array (fused).
// ---------------------------------------------------------------------------
__global__ __launch_bounds__(256) void prep_w_kernel(
    const float* __restrict__ Wq, const float* __restrict__ Wk,
    const float* __restrict__ Wv, __hip_bfloat16* __restrict__ Wt,
    int* __restrict__ counts)
{
    const int i = blockIdx.x * 256 + threadIdx.x;
    if (i < N_NODES) counts[i] = 0;
    if (i >= 3 * D * D) return;
    const int p = i >> 14;
    const int r = i & (D * D - 1);
    const int col = r >> 7;
    const int k = r & (D - 1);
    const float* W = (p == 0) ? Wq : (p == 1) ? Wk : Wv;
    Wt[i] = __float2bfloat16(W[k * D + col]);
}

// ---------------------------------------------------------------------------
// Projections via bf16 MFMA, f32 accum. Grid (ceil(N/32), 3); 256 thr = 4 waves.
// ---------------------------------------------------------------------------
__global__ __launch_bounds__(256) void proj_mfma_kernel(
    const float* __restrict__ x,
    const __hip_bfloat16* __restrict__ Wt,
    const float* __restrict__ bq, const float* __restrict__ bk,
    const float* __restrict__ bv,
    __hip_bfloat16* __restrict__ Qb,     // [N][128]
    __hip_bfloat16* __restrict__ KVi)    // [N][256]: [2d]=K, [2d+1]=V
{
    const int p    = blockIdx.y;
    const int m0   = blockIdx.x * 32;
    const int lane = threadIdx.x & 63;
    const int wv   = threadIdx.x >> 6;
    const int cb   = wv * 32;

    const short* Wp = (const short*)(Wt + p * D * D);

    floatx4 acc[2][2];
    #pragma unroll
    for (int a = 0; a < 2; ++a)
        #pragma unroll
        for (int b = 0; b < 2; ++b)
            acc[a][b] = (floatx4){0.f, 0.f, 0.f, 0.f};

    const int lr = lane & 15;
    const int lk = (lane >> 4) * 8;

    #pragma unroll
    for (int ks = 0; ks < 4; ++ks) {
        const int k0 = ks * 32 + lk;
        short8 afr[2];
        #pragma unroll
        for (int rt = 0; rt < 2; ++rt) {
            int node = m0 + rt * 16 + lr;
            if (node > N_NODES - 1) node = N_NODES - 1;   // clamp OOB loads
            const float4 f0 = *(const float4*)(x + node * D + k0);
            const float4 f1 = *(const float4*)(x + node * D + k0 + 4);
            afr[rt][0] = f2bfbits(f0.x); afr[rt][1] = f2bfbits(f0.y);
            afr[rt][2] = f2bfbits(f0.z); afr[rt][3] = f2bfbits(f0.w);
            afr[rt][4] = f2bfbits(f1.x); afr[rt][5] = f2bfbits(f1.y);
            afr[rt][6] = f2bfbits(f1.z); afr[rt][7] = f2bfbits(f1.w);
        }
        #pragma unroll
        for (int ct = 0; ct < 2; ++ct) {
            const int col = cb + ct * 16 + lr;
            const short8 bfr = *(const short8*)(Wp + col * D + k0);
            acc[0][ct] = __builtin_amdgcn_mfma_f32_16x16x32_bf16(afr[0], bfr, acc[0][ct], 0, 0, 0);
            acc[1][ct] = __builtin_amdgcn_mfma_f32_16x16x32_bf16(afr[1], bfr, acc[1][ct], 0, 0, 0);
        }
    }

    const float* bias = (p == 0) ? bq : (p == 1) ? bk : bv;
    #pragma unroll
    for (int rt = 0; rt < 2; ++rt) {
        #pragma unroll
        for (int ct = 0; ct < 2; ++ct) {
            const int col = cb + ct * 16 + lr;
            const float bsv = bias[col];
            #pragma unroll
            for (int r = 0; r < 4; ++r) {
                const int node = m0 + rt * 16 + (lane >> 4) * 4 + r;
                if (node < N_NODES) {
                    const float val = acc[rt][ct][r] + bsv;
                    if (p == 0)      Qb [node * D + col]              = __float2bfloat16(val);
                    else if (p == 1) KVi[node * 2 * D + 2 * col]      = __float2bfloat16(val);
                    else             KVi[node * 2 * D + 2 * col + 1]  = __float2bfloat16(val);
                }
            }
        }
    }
}

// ---------------------------------------------------------------------------
// CSR build: histogram -> 3-step exclusive scan -> scatter (srcs)
// ---------------------------------------------------------------------------
__global__ __launch_bounds__(256) void hist_kernel(
    const int* __restrict__ dst, int* __restrict__ counts)
{
    const int i = blockIdx.x * blockDim.x + threadIdx.x;
    const int stride = gridDim.x * blockDim.x;
    for (int e = i; e < N_EDGES; e += stride)
        atomicAdd(&counts[dst[e]], 1);
}

__global__ __launch_bounds__(SCAN_CHUNK) void scan_a_kernel(
    const int* __restrict__ counts, int* __restrict__ row_ptr,
    int* __restrict__ blksums)
{
    __shared__ int sd[SCAN_CHUNK];
    const int tid = threadIdx.x;
    const int i   = blockIdx.x * SCAN_CHUNK + tid;
    const int v   = (i < N_NODES) ? counts[i] : 0;
    sd[tid] = v;
    __syncthreads();
    #pragma unroll
    for (int off = 1; off < SCAN_CHUNK; off <<= 1) {
        int t = (tid >= off) ? sd[tid - off] : 0;
        __syncthreads();
        sd[tid] += t;
        __syncthreads();
    }
    if (i < N_NODES) row_ptr[i] = sd[tid] - v;
    if (tid == 0) blksums[blockIdx.x] = sd[SCAN_CHUNK - 1];
}

__global__ __launch_bounds__(SCAN_CHUNK) void scan_b_kernel(int* __restrict__ blksums)
{
    __shared__ int sd[SCAN_CHUNK];
    const int tid = threadIdx.x;
    const int v = (tid < NCHUNK) ? blksums[tid] : 0;
    sd[tid] = v;
    __syncthreads();
    #pragma unroll
    for (int off = 1; off < SCAN_CHUNK; off <<= 1) {
        int t = (tid >= off) ? sd[tid - off] : 0;
        __syncthreads();
        sd[tid] += t;
        __syncthreads();
    }
    if (tid < NCHUNK) blksums[tid] = sd[tid] - v;
}

__global__ __launch_bounds__(256) void scan_c_kernel(
    int* __restrict__ row_ptr, const int* __restrict__ blksums,
    int* __restrict__ cursor)
{
    const int i = blockIdx.x * blockDim.x + threadIdx.x;
    if (i < N_NODES) {
        const int rp = row_ptr[i] + blksums[i >> 8];
        row_ptr[i] = rp;
        cursor[i] = rp;
    }
    if (i == 0) row_ptr[N_NODES] = N_EDGES;
}

__global__ __launch_bounds__(256) void scatter_kernel(
    const int* __restrict__ dst, const int* __restrict__ src,
    int* __restrict__ cursor, int* __restrict__ srcs)
{
    const int i = blockIdx.x * blockDim.x + threadIdx.x;
    const int stride = gridDim.x * blockDim.x;
    for (int e = i; e < N_EDGES; e += stride) {
        const int pos = atomicAdd(&cursor[dst[e]], 1);
        srcs[pos] = src[e];
    }
}

// ---------------------------------------------------------------------------
// Aggregate: one wave per dst node, 4 edges per iteration (MLP).
// Lane l owns dims {2l,2l+1} (head l>>3); one contiguous 512B KVi row / edge.
// ---------------------------------------------------------------------------
__global__ __launch_bounds__(256) void aggregate_kernel(
    const int* __restrict__ row_ptr, const int* __restrict__ srcs,
    const __hip_bfloat16* __restrict__ Qb, const __hip_bfloat16* __restrict__ KVi,
    const float* __restrict__ x, float* __restrict__ out)
{
    const int lane = threadIdx.x & 63;
    const int t    = (blockIdx.x * blockDim.x + threadIdx.x) >> 6;
    if (t >= N_NODES) return;

    const unsigned int qbits = *(const unsigned int*)((const short*)Qb + t * D + 2 * lane);
    const float q0 = bfbits2f((unsigned short)(qbits & 0xffff));
    const float q1 = bfbits2f((unsigned short)(qbits >> 16));

    int i = row_ptr[t];
    const int rp1 = row_ptr[t + 1];

    float accx = 0.f, accy = 0.f, zh = 0.f;
    const short* KVs = (const short*)KVi;

    // 4-deep: 4 independent row-gathers in flight per wave
    for (; i + 4 <= rp1; i += 4) {
        const int s0 = srcs[i + 0];
        const int s1 = srcs[i + 1];
        const int s2 = srcs[i + 2];
        const int s3 = srcs[i + 3];
        const ushort4 kv0 = *(const ushort4*)(KVs + (size_t)s0 * 256 + 4 * lane);
        const ushort4 kv1 = *(const ushort4*)(KVs + (size_t)s1 * 256 + 4 * lane);
        const ushort4 kv2 = *(const ushort4*)(KVs + (size_t)s2 * 256 + 4 * lane);
        const ushort4 kv3 = *(const ushort4*)(KVs + (size_t)s3 * 256 + 4 * lane);

        float p0 = bfbits2f(kv0.x) * q0 + bfbits2f(kv0.z) * q1;
        float p1 = bfbits2f(kv1.x) * q0 + bfbits2f(kv1.z) * q1;
        float p2 = bfbits2f(kv2.x) * q0 + bfbits2f(kv2.z) * q1;
        float p3 = bfbits2f(kv3.x) * q0 + bfbits2f(kv3.z) * q1;

        p0 += __shfl_xor(p0, 1); p1 += __shfl_xor(p1, 1);
        p2 += __shfl_xor(p2, 1); p3 += __shfl_xor(p3, 1);
        p0 += __shfl_xor(p0, 2); p1 += __shfl_xor(p1, 2);
        p2 += __shfl_xor(p2, 2); p3 += __shfl_xor(p3, 2);
        p0 += __shfl_xor(p0, 4); p1 += __shfl_xor(p1, 4);
        p2 += __shfl_xor(p2, 4); p3 += __shfl_xor(p3, 4);

        const float w0 = __expf(fminf(fmaxf(p0 * 0.25f, -5.0f), 5.0f));
        const float w1 = __expf(fminf(fmaxf(p1 * 0.25f, -5.0f), 5.0f));
        const float w2 = __expf(fminf(fmaxf(p2 * 0.25f, -5.0f), 5.0f));
        const float w3 = __expf(fminf(fmaxf(p3 * 0.25f, -5.0f), 5.0f));

        accx += w0 * bfbits2f(kv0.y) + w1 * bfbits2f(kv1.y)
              + w2 * bfbits2f(kv2.y) + w3 * bfbits2f(kv3.y);
        accy += w0 * bfbits2f(kv0.w) + w1 * bfbits2f(kv1.w)
              + w2 * bfbits2f(kv2.w) + w3 * bfbits2f(kv3.w);
        zh   += (w0 + w1) + (w2 + w3);
    }
    // tail
    for (; i < rp1; ++i) {
        const int s = srcs[i];
        const ushort4 kv = *(const ushort4*)(KVs + (size_t)s * 256 + 4 * lane);
        float p = bfbits2f(kv.x) * q0 + bfbits2f(kv.z) * q1;
        p += __shfl_xor(p, 1);
        p += __shfl_xor(p, 2);
        p += __shfl_xor(p, 4);
        const float w = __expf(fminf(fmaxf(p * 0.25f, -5.0f), 5.0f));
        accx += w * bfbits2f(kv.y);
        accy += w * bfbits2f(kv.w);
        zh   += w;
    }

    const float inv = 1.0f / zh;
    const int base = t * D + 2 * lane;
    out[base + 0] = x[base + 0] + accx * inv;
    out[base + 1] = x[base + 1] + accy * inv;
}

// ---------------------------------------------------------------------------
extern "C" void kernel_launch(void* const* d_in, const int* in_sizes, int n_in,
                              void* d_out, int out_size, void* d_ws, size_t ws_size,
                              hipStream_t stream) {
    const float* x   = (const float*)d_in[0];
    const int*   src = (const int*)d_in[1];
    const int*   dst = (const int*)d_in[2];
    const float* Wq  = (const float*)d_in[3];
    const float* bq  = (const float*)d_in[4];
    const float* Wk  = (const float*)d_in[5];
    const float* bk  = (const float*)d_in[6];
    const float* Wv  = (const float*)d_in[7];
    const float* bv  = (const float*)d_in[8];

    __hip_bfloat16* Qb  = (__hip_bfloat16*)d_ws;                 // [N*D]
    __hip_bfloat16* KVi = Qb + (size_t)N_NODES * D;              // [N*2D]
    __hip_bfloat16* Wt  = KVi + (size_t)N_NODES * 2 * D;         // [3*D*D]
    int* counts   = (int*)(Wt + 3 * D * D);                      // [50048]
    int* row_ptr  = counts + 50048;                              // [50048]
    int* cursor   = row_ptr + 50048;                             // [50048]
    int* blksums  = cursor + 50048;                              // [256]
    int* srcs     = blksums + 256;                               // [800000]

    float* out = (float*)d_out;

    prep_w_kernel<<<196, 256, 0, stream>>>(Wq, Wk, Wv, Wt, counts);

    proj_mfma_kernel<<<dim3((N_NODES + 31) / 32, 3), 256, 0, stream>>>(
        x, Wt, bq, bk, bv, Qb, KVi);

    hist_kernel<<<1024, 256, 0, stream>>>(dst, counts);
    scan_a_kernel<<<NCHUNK, SCAN_CHUNK, 0, stream>>>(counts, row_ptr, blksums);
    scan_b_kernel<<<1, SCAN_CHUNK, 0, stream>>>(blksums);
    scan_c_kernel<<<(N_NODES + 255) / 256, 256, 0, stream>>>(row_ptr, blksums, cursor);
    scatter_kernel<<<1024, 256, 0, stream>>>(dst, src, cursor, srcs);

    aggregate_kernel<<<(N_NODES * 64 + 255) / 256, 256, 0, stream>>>(
        row_ptr, srcs, Qb, KVi, x, out);
}

// Round 6
// 276.455 us; speedup vs baseline: 3.2499x; 1.1434x over previous
//
#include <hip/hip_runtime.h>
#include <hip/hip_bf16.h>

#define N_NODES 50000
#define N_EDGES 800000
#define D 128
#define H 8
#define DH 16
#define SCAN_CHUNK 256
#define NCHUNK ((N_NODES + SCAN_CHUNK - 1) / SCAN_CHUNK)   // 196

typedef __attribute__((ext_vector_type(8))) short short8;
typedef __attribute__((ext_vector_type(4))) float floatx4;

__device__ __forceinline__ float bfbits2f(unsigned short u) {
    union { unsigned int i; float f; } c; c.i = ((unsigned int)u) << 16; return c.f;
}
__device__ __forceinline__ unsigned short f2bfbits(float f) {
    __hip_bfloat16 h = __float2bfloat16(f);
    return *reinterpret_cast<unsigned short*>(&h);
}

// ---------------------------------------------------------------------------
// Prep: Wt[p][col][k] = bf16(W_p[k][col]) + zero counts (fused).
// ---------------------------------------------------------------------------
__global__ __launch_bounds__(256) void prep_w_kernel(
    const float* __restrict__ Wq, const float* __restrict__ Wk,
    const float* __restrict__ Wv, __hip_bfloat16* __restrict__ Wt,
    int* __restrict__ counts)
{
    const int i = blockIdx.x * 256 + threadIdx.x;
    if (i < N_NODES) counts[i] = 0;
    if (i >= 3 * D * D) return;
    const int p = i >> 14;
    const int r = i & (D * D - 1);
    const int col = r >> 7;
    const int k = r & (D - 1);
    const float* W = (p == 0) ? Wq : (p == 1) ? Wk : Wv;
    Wt[i] = __float2bfloat16(W[k * D + col]);
}

// ---------------------------------------------------------------------------
// Projections: block = 4 waves, tile = 64 nodes x 384 cols (all 3 p).
// x staged once in LDS (bf16, +8-short row pad); wave w owns cols [32w,32w+32)
// of each p; 96 MFMAs/wave. Outputs:
//   Qt[col][node] (transposed; 8B packed stores)
//   KVi[node][128] u32: (K[c] | V[c]<<16) -> 64B-coalesced dword stores
// A: row=lane&15, k=(lane>>4)*8+j.  B: col=lane&15, k=(lane>>4)*8+j.
// D: col=lane&15, row=(lane>>4)*4+r.
// ---------------------------------------------------------------------------
__global__ __launch_bounds__(256) void proj_mfma_kernel(
    const float* __restrict__ x,
    const __hip_bfloat16* __restrict__ Wt,
    const float* __restrict__ bq, const float* __restrict__ bk,
    const float* __restrict__ bv,
    unsigned short* __restrict__ Qt,     // [D][N_NODES]
    unsigned int* __restrict__ KVi)      // [N_NODES][128]
{
    const int m0   = blockIdx.x * 64;
    const int tid  = threadIdx.x;
    const int lane = tid & 63;
    const int wv   = tid >> 6;
    const int cb   = wv * 32;
    const int lr   = lane & 15;
    const int hi   = lane >> 4;

    __shared__ short xs[64][136];   // +8 shorts pad: uniform bank spread

    // ---- stage x tile (64 rows x 128 f32 -> bf16 LDS), each thread 32 f32
    {
        const int row = tid >> 2;
        const int c0  = (tid & 3) * 32;
        int n = m0 + row; if (n >= N_NODES) n = N_NODES - 1;
        const float* xr = x + (size_t)n * D + c0;
        #pragma unroll
        for (int i = 0; i < 8; ++i) {
            const float4 f = *(const float4*)(xr + i * 4);
            short4 s;
            s.x = (short)f2bfbits(f.x); s.y = (short)f2bfbits(f.y);
            s.z = (short)f2bfbits(f.z); s.w = (short)f2bfbits(f.w);
            *(short4*)(&xs[row][c0 + i * 4]) = s;
        }
    }
    __syncthreads();

    floatx4 acc[3][4][2];   // [p][rt][ct]
    #pragma unroll
    for (int p = 0; p < 3; ++p)
        #pragma unroll
        for (int rt = 0; rt < 4; ++rt)
            #pragma unroll
            for (int ct = 0; ct < 2; ++ct)
                acc[p][rt][ct] = (floatx4){0.f, 0.f, 0.f, 0.f};

    const short* Wts = (const short*)Wt;

    #pragma unroll
    for (int ks = 0; ks < 4; ++ks) {
        const int k0 = ks * 32 + hi * 8;

        short8 bfr[3][2];
        #pragma unroll
        for (int p = 0; p < 3; ++p)
            #pragma unroll
            for (int ct = 0; ct < 2; ++ct) {
                const int col = cb + ct * 16 + lr;
                bfr[p][ct] = *(const short8*)(Wts + ((size_t)(p * D + col) * D + k0));
            }

        short8 afr[4];
        #pragma unroll
        for (int rt = 0; rt < 4; ++rt)
            afr[rt] = *(const short8*)(&xs[rt * 16 + lr][k0]);

        #pragma unroll
        for (int p = 0; p < 3; ++p)
            #pragma unroll
            for (int ct = 0; ct < 2; ++ct)
                #pragma unroll
                for (int rt = 0; rt < 4; ++rt)
                    acc[p][rt][ct] = __builtin_amdgcn_mfma_f32_16x16x32_bf16(
                        afr[rt], bfr[p][ct], acc[p][rt][ct], 0, 0, 0);
    }

    // ---- epilogue: bias + packed stores (no transpose needed)
    #pragma unroll
    for (int ct = 0; ct < 2; ++ct) {
        const int col = cb + ct * 16 + lr;
        const float bqv = bq[col], bkv = bk[col], bvv = bv[col];
        #pragma unroll
        for (int rt = 0; rt < 4; ++rt) {
            const int node0 = m0 + rt * 16 + hi * 4;
            if (node0 < N_NODES) {   // node0 % 4 == 0 and N % 4 == 0 -> all 4 valid
                ushort4 qs;
                qs.x = f2bfbits(acc[0][rt][ct][0] + bqv);
                qs.y = f2bfbits(acc[0][rt][ct][1] + bqv);
                qs.z = f2bfbits(acc[0][rt][ct][2] + bqv);
                qs.w = f2bfbits(acc[0][rt][ct][3] + bqv);
                *(ushort4*)(Qt + (size_t)col * N_NODES + node0) = qs;
                #pragma unroll
                for (int r = 0; r < 4; ++r) {
                    const unsigned int kk = f2bfbits(acc[1][rt][ct][r] + bkv);
                    const unsigned int vv = f2bfbits(acc[2][rt][ct][r] + bvv);
                    KVi[(size_t)(node0 + r) * 128 + col] = kk | (vv << 16);
                }
            }
        }
    }
}

// ---------------------------------------------------------------------------
// CSR build: histogram -> 3-step exclusive scan -> scatter (srcs)
// ---------------------------------------------------------------------------
__global__ __launch_bounds__(256) void hist_kernel(
    const int* __restrict__ dst, int* __restrict__ counts)
{
    const int i = blockIdx.x * blockDim.x + threadIdx.x;
    const int stride = gridDim.x * blockDim.x;
    for (int e = i; e < N_EDGES; e += stride)
        atomicAdd(&counts[dst[e]], 1);
}

__global__ __launch_bounds__(SCAN_CHUNK) void scan_a_kernel(
    const int* __restrict__ counts, int* __restrict__ row_ptr,
    int* __restrict__ blksums)
{
    __shared__ int sd[SCAN_CHUNK];
    const int tid = threadIdx.x;
    const int i   = blockIdx.x * SCAN_CHUNK + tid;
    const int v   = (i < N_NODES) ? counts[i] : 0;
    sd[tid] = v;
    __syncthreads();
    #pragma unroll
    for (int off = 1; off < SCAN_CHUNK; off <<= 1) {
        int t = (tid >= off) ? sd[tid - off] : 0;
        __syncthreads();
        sd[tid] += t;
        __syncthreads();
    }
    if (i < N_NODES) row_ptr[i] = sd[tid] - v;
    if (tid == 0) blksums[blockIdx.x] = sd[SCAN_CHUNK - 1];
}

__global__ __launch_bounds__(SCAN_CHUNK) void scan_b_kernel(int* __restrict__ blksums)
{
    __shared__ int sd[SCAN_CHUNK];
    const int tid = threadIdx.x;
    const int v = (tid < NCHUNK) ? blksums[tid] : 0;
    sd[tid] = v;
    __syncthreads();
    #pragma unroll
    for (int off = 1; off < SCAN_CHUNK; off <<= 1) {
        int t = (tid >= off) ? sd[tid - off] : 0;
        __syncthreads();
        sd[tid] += t;
        __syncthreads();
    }
    if (tid < NCHUNK) blksums[tid] = sd[tid] - v;
}

__global__ __launch_bounds__(256) void scan_c_kernel(
    int* __restrict__ row_ptr, const int* __restrict__ blksums,
    int* __restrict__ cursor)
{
    const int i = blockIdx.x * blockDim.x + threadIdx.x;
    if (i < N_NODES) {
        const int rp = row_ptr[i] + blksums[i >> 8];
        row_ptr[i] = rp;
        cursor[i] = rp;
    }
    if (i == 0) row_ptr[N_NODES] = N_EDGES;
}

__global__ __launch_bounds__(256) void scatter_kernel(
    const int* __restrict__ dst, const int* __restrict__ src,
    int* __restrict__ cursor, int* __restrict__ srcs)
{
    const int i = blockIdx.x * blockDim.x + threadIdx.x;
    const int stride = gridDim.x * blockDim.x;
    for (int e = i; e < N_EDGES; e += stride) {
        const int pos = atomicAdd(&cursor[dst[e]], 1);
        srcs[pos] = src[e];
    }
}

// ---------------------------------------------------------------------------
// Aggregate: one wave per dst node, 4 edges/iter. Lane l owns dims {2l,2l+1}
// (head l>>3); one contiguous 512B KVi row per edge. Q from transposed Qt.
// ---------------------------------------------------------------------------
__global__ __launch_bounds__(256) void aggregate_kernel(
    const int* __restrict__ row_ptr, const int* __restrict__ srcs,
    const unsigned short* __restrict__ Qt, const unsigned int* __restrict__ KVi,
    const float* __restrict__ x, float* __restrict__ out)
{
    const int lane = threadIdx.x & 63;
    const int t    = (blockIdx.x * blockDim.x + threadIdx.x) >> 6;
    if (t >= N_NODES) return;

    const float q0 = bfbits2f(Qt[(size_t)(2 * lane)     * N_NODES + t]);
    const float q1 = bfbits2f(Qt[(size_t)(2 * lane + 1) * N_NODES + t]);

    int i = row_ptr[t];
    const int rp1 = row_ptr[t + 1];

    float accx = 0.f, accy = 0.f, zh = 0.f;
    const unsigned long long* KVs = (const unsigned long long*)KVi;

    for (; i + 4 <= rp1; i += 4) {
        const int s0 = srcs[i + 0];
        const int s1 = srcs[i + 1];
        const int s2 = srcs[i + 2];
        const int s3 = srcs[i + 3];
        const unsigned long long kv0 = KVs[(size_t)s0 * 64 + lane];
        const unsigned long long kv1 = KVs[(size_t)s1 * 64 + lane];
        const unsigned long long kv2 = KVs[(size_t)s2 * 64 + lane];
        const unsigned long long kv3 = KVs[(size_t)s3 * 64 + lane];

        float p0 = bfbits2f((unsigned short)kv0) * q0 + bfbits2f((unsigned short)(kv0 >> 32)) * q1;
        float p1 = bfbits2f((unsigned short)kv1) * q0 + bfbits2f((unsigned short)(kv1 >> 32)) * q1;
        float p2 = bfbits2f((unsigned short)kv2) * q0 + bfbits2f((unsigned short)(kv2 >> 32)) * q1;
        float p3 = bfbits2f((unsigned short)kv3) * q0 + bfbits2f((unsigned short)(kv3 >> 32)) * q1;

        p0 += __shfl_xor(p0, 1); p1 += __shfl_xor(p1, 1);
        p2 += __shfl_xor(p2, 1); p3 += __shfl_xor(p3, 1);
        p0 += __shfl_xor(p0, 2); p1 += __shfl_xor(p1, 2);
        p2 += __shfl_xor(p2, 2); p3 += __shfl_xor(p3, 2);
        p0 += __shfl_xor(p0, 4); p1 += __shfl_xor(p1, 4);
        p2 += __shfl_xor(p2, 4); p3 += __shfl_xor(p3, 4);

        const float w0 = __expf(fminf(fmaxf(p0 * 0.25f, -5.0f), 5.0f));
        const float w1 = __expf(fminf(fmaxf(p1 * 0.25f, -5.0f), 5.0f));
        const float w2 = __expf(fminf(fmaxf(p2 * 0.25f, -5.0f), 5.0f));
        const float w3 = __expf(fminf(fmaxf(p3 * 0.25f, -5.0f), 5.0f));

        accx += w0 * bfbits2f((unsigned short)(kv0 >> 16)) + w1 * bfbits2f((unsigned short)(kv1 >> 16))
              + w2 * bfbits2f((unsigned short)(kv2 >> 16)) + w3 * bfbits2f((unsigned short)(kv3 >> 16));
        accy += w0 * bfbits2f((unsigned short)(kv0 >> 48)) + w1 * bfbits2f((unsigned short)(kv1 >> 48))
              + w2 * bfbits2f((unsigned short)(kv2 >> 48)) + w3 * bfbits2f((unsigned short)(kv3 >> 48));
        zh   += (w0 + w1) + (w2 + w3);
    }
    for (; i < rp1; ++i) {
        const int s = srcs[i];
        const unsigned long long kv = KVs[(size_t)s * 64 + lane];
        float p = bfbits2f((unsigned short)kv) * q0 + bfbits2f((unsigned short)(kv >> 32)) * q1;
        p += __shfl_xor(p, 1);
        p += __shfl_xor(p, 2);
        p += __shfl_xor(p, 4);
        const float w = __expf(fminf(fmaxf(p * 0.25f, -5.0f), 5.0f));
        accx += w * bfbits2f((unsigned short)(kv >> 16));
        accy += w * bfbits2f((unsigned short)(kv >> 48));
        zh   += w;
    }

    const float inv = 1.0f / zh;
    const int base = t * D + 2 * lane;
    out[base + 0] = x[base + 0] + accx * inv;
    out[base + 1] = x[base + 1] + accy * inv;
}

// ---------------------------------------------------------------------------
extern "C" void kernel_launch(void* const* d_in, const int* in_sizes, int n_in,
                              void* d_out, int out_size, void* d_ws, size_t ws_size,
                              hipStream_t stream) {
    const float* x   = (const float*)d_in[0];
    const int*   src = (const int*)d_in[1];
    const int*   dst = (const int*)d_in[2];
    const float* Wq  = (const float*)d_in[3];
    const float* bq  = (const float*)d_in[4];
    const float* Wk  = (const float*)d_in[5];
    const float* bk  = (const float*)d_in[6];
    const float* Wv  = (const float*)d_in[7];
    const float* bv  = (const float*)d_in[8];

    unsigned short* Qt  = (unsigned short*)d_ws;                  // [D][N]
    unsigned int*   KVi = (unsigned int*)(Qt + (size_t)D * N_NODES); // [N][128] u32
    __hip_bfloat16* Wt  = (__hip_bfloat16*)(KVi + (size_t)N_NODES * 128);
    int* counts   = (int*)(Wt + 3 * D * D);                      // [50048]
    int* row_ptr  = counts + 50048;                              // [50048]
    int* cursor   = row_ptr + 50048;                             // [50048]
    int* blksums  = cursor + 50048;                              // [256]
    int* srcs     = blksums + 256;                               // [800000]

    float* out = (float*)d_out;

    prep_w_kernel<<<196, 256, 0, stream>>>(Wq, Wk, Wv, Wt, counts);

    proj_mfma_kernel<<<(N_NODES + 63) / 64, 256, 0, stream>>>(
        x, Wt, bq, bk, bv, Qt, KVi);

    hist_kernel<<<1024, 256, 0, stream>>>(dst, counts);
    scan_a_kernel<<<NCHUNK, SCAN_CHUNK, 0, stream>>>(counts, row_ptr, blksums);
    scan_b_kernel<<<1, SCAN_CHUNK, 0, stream>>>(blksums);
    scan_c_kernel<<<(N_NODES + 255) / 256, 256, 0, stream>>>(row_ptr, blksums, cursor);
    scatter_kernel<<<1024, 256, 0, stream>>>(dst, src, cursor, srcs);

    aggregate_kernel<<<(N_NODES * 64 + 255) / 256, 256, 0, stream>>>(
        row_ptr, srcs, Qt, KVi, x, out);
}

// Round 7
// 275.635 us; speedup vs baseline: 3.2595x; 1.0030x over previous
//
#include <hip/hip_runtime.h>
#include <hip/hip_bf16.h>

#define N_NODES 50000
#define N_EDGES 800000
#define D 128
#define H 8

#define PROJ_BLOCKS ((N_NODES + 63) / 64)   // 782
#define HIST_BLOCKS 1024
#define SCAN_T 1024
#define PER_T 50                            // 1000 threads cover 50000 nodes

typedef __attribute__((ext_vector_type(8))) short short8;
typedef __attribute__((ext_vector_type(4))) float floatx4;

__device__ __forceinline__ float bfbits2f(unsigned short u) {
    union { unsigned int i; float f; } c; c.i = ((unsigned int)u) << 16; return c.f;
}
__device__ __forceinline__ unsigned short f2bfbits(float f) {
    __hip_bfloat16 h = __float2bfloat16(f);
    return *reinterpret_cast<unsigned short*>(&h);
}

// ---------------------------------------------------------------------------
// Prep: Wt[p][col][k] = bf16(W_p[k][col]) + zero counts (fused).
// ---------------------------------------------------------------------------
__global__ __launch_bounds__(256) void prep_w_kernel(
    const float* __restrict__ Wq, const float* __restrict__ Wk,
    const float* __restrict__ Wv, __hip_bfloat16* __restrict__ Wt,
    int* __restrict__ counts)
{
    const int i = blockIdx.x * 256 + threadIdx.x;
    if (i < N_NODES) counts[i] = 0;
    if (i >= 3 * D * D) return;
    const int p = i >> 14;
    const int r = i & (D * D - 1);
    const int col = r >> 7;
    const int k = r & (D - 1);
    const float* W = (p == 0) ? Wq : (p == 1) ? Wk : Wv;
    Wt[i] = __float2bfloat16(W[k * D + col]);
}

// ---------------------------------------------------------------------------
// Fused: blocks [0,PROJ_BLOCKS) do the MFMA projections; blocks
// [PROJ_BLOCKS, PROJ_BLOCKS+HIST_BLOCKS) do the dst histogram. Independent
// work overlapped in one dispatch.
//
// Proj tile: 64 nodes x 384 cols (all 3 p), 4 waves. x staged in LDS bf16.
// Outputs: Qb[node][128] bf16 (row-major via in-LDS transpose epilogue),
//          KVi[node][128] u32 = (K[c] | V[c]<<16).
// ---------------------------------------------------------------------------
__global__ __launch_bounds__(256) void proj_hist_kernel(
    const float* __restrict__ x,
    const __hip_bfloat16* __restrict__ Wt,
    const float* __restrict__ bq, const float* __restrict__ bk,
    const float* __restrict__ bv,
    unsigned short* __restrict__ Qb,     // [N][128] bf16 bits
    unsigned int* __restrict__ KVi,      // [N][128] u32
    const int* __restrict__ dst, int* __restrict__ counts)
{
    const int tid = threadIdx.x;

    // ---------------- histogram blocks ----------------
    if (blockIdx.x >= PROJ_BLOCKS) {
        const int i = (blockIdx.x - PROJ_BLOCKS) * 256 + tid;
        const int stride = HIST_BLOCKS * 256;
        for (int e = i; e < N_EDGES; e += stride)
            atomicAdd(&counts[dst[e]], 1);
        return;
    }

    // ---------------- projection blocks ----------------
    const int m0   = blockIdx.x * 64;
    const int lane = tid & 63;
    const int wv   = tid >> 6;
    const int cb   = wv * 32;
    const int lr   = lane & 15;
    const int hi   = lane >> 4;

    __shared__ short xs[64][136];   // +8-short row pad

    // stage x tile (64 rows x 128 f32 -> bf16 LDS), each thread 32 f32
    {
        const int row = tid >> 2;
        const int c0  = (tid & 3) * 32;
        int n = m0 + row; if (n >= N_NODES) n = N_NODES - 1;
        const float* xr = x + (size_t)n * D + c0;
        #pragma unroll
        for (int i = 0; i < 8; ++i) {
            const float4 f = *(const float4*)(xr + i * 4);
            short4 s;
            s.x = (short)f2bfbits(f.x); s.y = (short)f2bfbits(f.y);
            s.z = (short)f2bfbits(f.z); s.w = (short)f2bfbits(f.w);
            *(short4*)(&xs[row][c0 + i * 4]) = s;
        }
    }
    __syncthreads();

    floatx4 acc[3][4][2];   // [p][rt][ct]
    #pragma unroll
    for (int p = 0; p < 3; ++p)
        #pragma unroll
        for (int rt = 0; rt < 4; ++rt)
            #pragma unroll
            for (int ct = 0; ct < 2; ++ct)
                acc[p][rt][ct] = (floatx4){0.f, 0.f, 0.f, 0.f};

    const short* Wts = (const short*)Wt;

    #pragma unroll
    for (int ks = 0; ks < 4; ++ks) {
        const int k0 = ks * 32 + hi * 8;

        short8 bfr[3][2];
        #pragma unroll
        for (int p = 0; p < 3; ++p)
            #pragma unroll
            for (int ct = 0; ct < 2; ++ct) {
                const int col = cb + ct * 16 + lr;
                bfr[p][ct] = *(const short8*)(Wts + ((size_t)(p * D + col) * D + k0));
            }

        short8 afr[4];
        #pragma unroll
        for (int rt = 0; rt < 4; ++rt)
            afr[rt] = *(const short8*)(&xs[rt * 16 + lr][k0]);

        #pragma unroll
        for (int p = 0; p < 3; ++p)
            #pragma unroll
            for (int ct = 0; ct < 2; ++ct)
                #pragma unroll
                for (int rt = 0; rt < 4; ++rt)
                    acc[p][rt][ct] = __builtin_amdgcn_mfma_f32_16x16x32_bf16(
                        afr[rt], bfr[p][ct], acc[p][rt][ct], 0, 0, 0);
    }

    // ---- KVi: bias + packed u32 stores (already coalesced per 16 lanes)
    #pragma unroll
    for (int ct = 0; ct < 2; ++ct) {
        const int col = cb + ct * 16 + lr;
        const float bkv = bk[col], bvv = bv[col];
        #pragma unroll
        for (int rt = 0; rt < 4; ++rt) {
            const int node0 = m0 + rt * 16 + hi * 4;
            if (node0 < N_NODES) {   // node0%4==0, N%4==0 -> all 4 valid
                #pragma unroll
                for (int r = 0; r < 4; ++r) {
                    const unsigned int kk = f2bfbits(acc[1][rt][ct][r] + bkv);
                    const unsigned int vv = f2bfbits(acc[2][rt][ct][r] + bvv);
                    KVi[(size_t)(node0 + r) * 128 + col] = kk | (vv << 16);
                }
            }
        }
    }

    // ---- Q: transpose through LDS, then coalesced row-major stores
    __syncthreads();   // xs reads in K-loop done block-wide before overwrite
    #pragma unroll
    for (int ct = 0; ct < 2; ++ct) {
        const int col = cb + ct * 16 + lr;
        const float bqv = bq[col];
        #pragma unroll
        for (int rt = 0; rt < 4; ++rt) {
            const int nloc = rt * 16 + hi * 4;
            #pragma unroll
            for (int r = 0; r < 4; ++r)
                xs[nloc + r][col] = (short)f2bfbits(acc[0][rt][ct][r] + bqv);
        }
    }
    __syncthreads();
    {
        const int row = tid >> 2;          // 0..63
        const int c0  = (tid & 3) * 32;    // shorts
        const int n   = m0 + row;
        if (n < N_NODES) {
            int4* dstp = (int4*)(Qb + (size_t)n * D + c0);
            const int4* srcp = (const int4*)(&xs[row][c0]);
            #pragma unroll
            for (int i = 0; i < 4; ++i) dstp[i] = srcp[i];
        }
    }
}

// ---------------------------------------------------------------------------
// Single-block exclusive scan of counts -> row_ptr, cursor (+ sentinel).
// 1000 active threads x 50 elements; wave shfl scan + LDS across waves.
// ---------------------------------------------------------------------------
__global__ __launch_bounds__(SCAN_T) void scan_kernel(
    const int* __restrict__ counts, int* __restrict__ row_ptr,
    int* __restrict__ cursor)
{
    __shared__ int wsum[16];
    const int tid  = threadIdx.x;
    const int base = tid * PER_T;

    int tot = 0;
    if (tid < 1000) {
        #pragma unroll 10
        for (int j = 0; j < PER_T; ++j) tot += counts[base + j];
    }

    // wave-inclusive scan
    int incl = tot;
    #pragma unroll
    for (int off = 1; off < 64; off <<= 1) {
        const int v = __shfl_up(incl, off);
        if ((tid & 63) >= off) incl += v;
    }
    if ((tid & 63) == 63) wsum[tid >> 6] = incl;
    __syncthreads();
    if (tid == 0) {
        int run = 0;
        #pragma unroll
        for (int w = 0; w < 16; ++w) { const int v = wsum[w]; wsum[w] = run; run += v; }
    }
    __syncthreads();

    if (tid < 1000) {
        int run = (incl - tot) + wsum[tid >> 6];   // exclusive prefix
        #pragma unroll 10
        for (int j = 0; j < PER_T; ++j) {
            const int c = counts[base + j];
            row_ptr[base + j] = run;
            cursor[base + j]  = run;
            run += c;
        }
    }
    if (tid == 0) row_ptr[N_NODES] = N_EDGES;
}

// ---------------------------------------------------------------------------
__global__ __launch_bounds__(256) void scatter_kernel(
    const int* __restrict__ dst, const int* __restrict__ src,
    int* __restrict__ cursor, int* __restrict__ srcs)
{
    const int i = blockIdx.x * blockDim.x + threadIdx.x;
    const int stride = gridDim.x * blockDim.x;
    for (int e = i; e < N_EDGES; e += stride) {
        const int pos = atomicAdd(&cursor[dst[e]], 1);
        srcs[pos] = src[e];
    }
}

// ---------------------------------------------------------------------------
// Aggregate: one wave per dst node, 4 edges/iter. Lane l owns dims {2l,2l+1}
// (head l>>3); one contiguous 512B KVi row per edge; Q row-major (4B/lane).
// ---------------------------------------------------------------------------
__global__ __launch_bounds__(256) void aggregate_kernel(
    const int* __restrict__ row_ptr, const int* __restrict__ srcs,
    const unsigned short* __restrict__ Qb, const unsigned int* __restrict__ KVi,
    const float* __restrict__ x, float* __restrict__ out)
{
    const int lane = threadIdx.x & 63;
    const int t    = (blockIdx.x * blockDim.x + threadIdx.x) >> 6;
    if (t >= N_NODES) return;

    const unsigned int qbits = *(const unsigned int*)(Qb + (size_t)t * D + 2 * lane);
    const float q0 = bfbits2f((unsigned short)(qbits & 0xffff));
    const float q1 = bfbits2f((unsigned short)(qbits >> 16));

    int i = row_ptr[t];
    const int rp1 = row_ptr[t + 1];

    float accx = 0.f, accy = 0.f, zh = 0.f;
    const unsigned long long* KVs = (const unsigned long long*)KVi;

    for (; i + 4 <= rp1; i += 4) {
        const int s0 = srcs[i + 0];
        const int s1 = srcs[i + 1];
        const int s2 = srcs[i + 2];
        const int s3 = srcs[i + 3];
        const unsigned long long kv0 = KVs[(size_t)s0 * 64 + lane];
        const unsigned long long kv1 = KVs[(size_t)s1 * 64 + lane];
        const unsigned long long kv2 = KVs[(size_t)s2 * 64 + lane];
        const unsigned long long kv3 = KVs[(size_t)s3 * 64 + lane];

        float p0 = bfbits2f((unsigned short)kv0) * q0 + bfbits2f((unsigned short)(kv0 >> 32)) * q1;
        float p1 = bfbits2f((unsigned short)kv1) * q0 + bfbits2f((unsigned short)(kv1 >> 32)) * q1;
        float p2 = bfbits2f((unsigned short)kv2) * q0 + bfbits2f((unsigned short)(kv2 >> 32)) * q1;
        float p3 = bfbits2f((unsigned short)kv3) * q0 + bfbits2f((unsigned short)(kv3 >> 32)) * q1;

        p0 += __shfl_xor(p0, 1); p1 += __shfl_xor(p1, 1);
        p2 += __shfl_xor(p2, 1); p3 += __shfl_xor(p3, 1);
        p0 += __shfl_xor(p0, 2); p1 += __shfl_xor(p1, 2);
        p2 += __shfl_xor(p2, 2); p3 += __shfl_xor(p3, 2);
        p0 += __shfl_xor(p0, 4); p1 += __shfl_xor(p1, 4);
        p2 += __shfl_xor(p2, 4); p3 += __shfl_xor(p3, 4);

        const float w0 = __expf(fminf(fmaxf(p0 * 0.25f, -5.0f), 5.0f));
        const float w1 = __expf(fminf(fmaxf(p1 * 0.25f, -5.0f), 5.0f));
        const float w2 = __expf(fminf(fmaxf(p2 * 0.25f, -5.0f), 5.0f));
        const float w3 = __expf(fminf(fmaxf(p3 * 0.25f, -5.0f), 5.0f));

        accx += w0 * bfbits2f((unsigned short)(kv0 >> 16)) + w1 * bfbits2f((unsigned short)(kv1 >> 16))
              + w2 * bfbits2f((unsigned short)(kv2 >> 16)) + w3 * bfbits2f((unsigned short)(kv3 >> 16));
        accy += w0 * bfbits2f((unsigned short)(kv0 >> 48)) + w1 * bfbits2f((unsigned short)(kv1 >> 48))
              + w2 * bfbits2f((unsigned short)(kv2 >> 48)) + w3 * bfbits2f((unsigned short)(kv3 >> 48));
        zh   += (w0 + w1) + (w2 + w3);
    }
    for (; i < rp1; ++i) {
        const int s = srcs[i];
        const unsigned long long kv = KVs[(size_t)s * 64 + lane];
        float p = bfbits2f((unsigned short)kv) * q0 + bfbits2f((unsigned short)(kv >> 32)) * q1;
        p += __shfl_xor(p, 1);
        p += __shfl_xor(p, 2);
        p += __shfl_xor(p, 4);
        const float w = __expf(fminf(fmaxf(p * 0.25f, -5.0f), 5.0f));
        accx += w * bfbits2f((unsigned short)(kv >> 16));
        accy += w * bfbits2f((unsigned short)(kv >> 48));
        zh   += w;
    }

    const float inv = 1.0f / zh;
    const int base = t * D + 2 * lane;
    out[base + 0] = x[base + 0] + accx * inv;
    out[base + 1] = x[base + 1] + accy * inv;
}

// ---------------------------------------------------------------------------
extern "C" void kernel_launch(void* const* d_in, const int* in_sizes, int n_in,
                              void* d_out, int out_size, void* d_ws, size_t ws_size,
                              hipStream_t stream) {
    const float* x   = (const float*)d_in[0];
    const int*   src = (const int*)d_in[1];
    const int*   dst = (const int*)d_in[2];
    const float* Wq  = (const float*)d_in[3];
    const float* bq  = (const float*)d_in[4];
    const float* Wk  = (const float*)d_in[5];
    const float* bk  = (const float*)d_in[6];
    const float* Wv  = (const float*)d_in[7];
    const float* bv  = (const float*)d_in[8];

    unsigned short* Qb  = (unsigned short*)d_ws;                        // [N][128] bf16
    unsigned int*   KVi = (unsigned int*)(Qb + (size_t)N_NODES * D);    // [N][128] u32
    __hip_bfloat16* Wt  = (__hip_bfloat16*)(KVi + (size_t)N_NODES * 128);
    int* counts   = (int*)(Wt + 3 * D * D);                             // [N]
    int* row_ptr  = counts + 50048;                                     // [N+1]
    int* cursor   = row_ptr + 50048;                                    // [N]
    int* srcs     = cursor + 50048;                                     // [E]

    float* out = (float*)d_out;

    prep_w_kernel<<<196, 256, 0, stream>>>(Wq, Wk, Wv, Wt, counts);

    proj_hist_kernel<<<PROJ_BLOCKS + HIST_BLOCKS, 256, 0, stream>>>(
        x, Wt, bq, bk, bv, Qb, KVi, dst, counts);

    scan_kernel<<<1, SCAN_T, 0, stream>>>(counts, row_ptr, cursor);

    scatter_kernel<<<1024, 256, 0, stream>>>(dst, src, cursor, srcs);

    aggregate_kernel<<<(N_NODES * 64 + 255) / 256, 256, 0, stream>>>(
        row_ptr, srcs, Qb, KVi, x, out);
}